// Round 1
// baseline (559.989 us; speedup 1.0000x reference)
//
#include <hip/hip_runtime.h>

#define NF 64
#define KEXP 50
#define TBL 8192
#define CUTF 5.0f
#define LOG2C 0.6931471805599453f

__device__ __forceinline__ float sspf(float x) {
    // softplus(x) - log(2), numerically stable
    return fmaxf(x, 0.0f) + log1pf(expf(-fabsf(x))) - LOG2C;
}

// ---------------------------------------------------------------------------
// Build filt(d) lookup table: TBL entries x NF features.
// filt(d) = ssp(rbf(d) @ f_w1.T + f_b1) @ f_w2.T + f_b2
// ---------------------------------------------------------------------------
__global__ void build_table_k(const float* __restrict__ f_w1, const float* __restrict__ f_b1,
                              const float* __restrict__ f_w2, const float* __restrict__ f_b2,
                              float* __restrict__ table) {
    __shared__ float rbf_s[KEXP];
    __shared__ float s_s[NF];
    const int t = blockIdx.x;
    const int f = threadIdx.x; // 0..63
    const float d = (float)t * (CUTF / (float)(TBL - 1));
    const float delta = CUTF / (float)(KEXP - 1);
    const float coeff = -0.5f / (delta * delta);
    if (f < KEXP) {
        float dd = d - (float)f * delta;
        rbf_s[f] = expf(coeff * dd * dd);
    }
    __syncthreads();
    float t1 = f_b1[f];
    for (int k = 0; k < KEXP; ++k) t1 = fmaf(rbf_s[k], f_w1[f * KEXP + k], t1);
    s_s[f] = sspf(t1);
    __syncthreads();
    float t2 = f_b2[f];
    for (int k = 0; k < NF; ++k) t2 = fmaf(s_s[k], f_w2[f * NF + k], t2);
    table[t * NF + f] = t2;
}

// ---------------------------------------------------------------------------
// h = x @ lin_w.T + lin_b   (wave per node, lane = output feature)
// ---------------------------------------------------------------------------
__global__ void node_lin_k(const float* __restrict__ x, const float* __restrict__ w,
                           const float* __restrict__ b, float* __restrict__ h, int n_nodes) {
    __shared__ float wT[NF][NF + 1];
    const int tid = threadIdx.x;
    for (int idx = tid; idx < NF * NF; idx += blockDim.x) {
        wT[idx & (NF - 1)][idx >> 6] = w[idx]; // w[f][k] -> wT[k][f]
    }
    __syncthreads();
    const int lane = tid & 63;
    const int nwaves = (gridDim.x * blockDim.x) >> 6;
    const int gw = (blockIdx.x * blockDim.x + tid) >> 6;
    const float bias = b[lane];
    for (int n = gw; n < n_nodes; n += nwaves) {
        const int nu = __builtin_amdgcn_readfirstlane(n);
        const float* xr = x + (size_t)nu * NF;  // wave-uniform -> scalar loads
        float acc = bias;
        #pragma unroll
        for (int k = 0; k < NF; ++k) acc = fmaf(xr[k], wT[k][lane], acc);
        h[(size_t)nu * NF + lane] = acc;
    }
}

// ---------------------------------------------------------------------------
// Edge kernel: wave per edge-batch of 64; lane = feature.
// filt via table lerp; msg = h[src]*filt; atomicAdd into agg[dst].
// ---------------------------------------------------------------------------
__global__ void edge_k(const int* __restrict__ nbr, const float* __restrict__ dist,
                       const float* __restrict__ h, const float* __restrict__ table,
                       float* __restrict__ agg, int n_edges) {
    const int tid = threadIdx.x;
    const int lane = tid & 63;
    const int nwaves = (gridDim.x * blockDim.x) >> 6;
    const int gw = (blockIdx.x * blockDim.x + tid) >> 6;
    const float scale = (float)(TBL - 1) / CUTF;
    const int nbatch = n_edges >> 6;
    for (int bb = gw; bb < nbatch; bb += nwaves) {
        const int e0 = bb << 6;
        // coalesced per-lane metadata for 64 edges
        int src = nbr[e0 + lane];
        int dst = nbr[n_edges + e0 + lane];
        float d = dist[e0 + lane];
        float xx = d * scale;
        int i0 = (int)xx;
        i0 = max(0, min(i0, TBL - 2));
        float frac = xx - (float)i0;
        #pragma unroll 4
        for (int j = 0; j < 64; ++j) {
            const int sj = __shfl(src, j);
            const int dj = __shfl(dst, j);
            const int ij = __shfl(i0, j);
            const float fj = __shfl(frac, j);
            const float t0 = table[ij * NF + lane];
            const float t1 = table[(ij + 1) * NF + lane];
            const float filt = fmaf(fj, t1 - t0, t0);
            const float hv = h[(size_t)sj * NF + lane];
            atomicAdd(agg + (size_t)dj * NF + lane, hv * filt);
        }
    }
    // tail (n_edges not a multiple of 64): global wave 0 handles serially
    if (gw == 0) {
        for (int e = nbatch << 6; e < n_edges; ++e) {
            const int sj = nbr[e];
            const int dj = nbr[n_edges + e];
            const float d = dist[e];
            float xx = d * scale;
            int ij = (int)xx;
            ij = max(0, min(ij, TBL - 2));
            const float fj = xx - (float)ij;
            const float t0 = table[ij * NF + lane];
            const float t1 = table[(ij + 1) * NF + lane];
            const float filt = fmaf(fj, t1 - t0, t0);
            const float hv = h[(size_t)sj * NF + lane];
            atomicAdd(agg + (size_t)dj * NF + lane, hv * filt);
        }
    }
}

// ---------------------------------------------------------------------------
// out = ssp(agg @ m_w1.T + m_b1) @ m_w2.T + m_b2   (wave per node)
// ---------------------------------------------------------------------------
__global__ void out_mlp_k(const float* __restrict__ agg,
                          const float* __restrict__ w1, const float* __restrict__ b1,
                          const float* __restrict__ w2, const float* __restrict__ b2,
                          float* __restrict__ out, int n_nodes) {
    __shared__ float w1T[NF][NF + 1];
    __shared__ float w2T[NF][NF + 1];
    const int tid = threadIdx.x;
    for (int idx = tid; idx < NF * NF; idx += blockDim.x) {
        const int f = idx >> 6, k = idx & (NF - 1);
        w1T[k][f] = w1[idx];
        w2T[k][f] = w2[idx];
    }
    __syncthreads();
    const int lane = tid & 63;
    const int nwaves = (gridDim.x * blockDim.x) >> 6;
    const int gw = (blockIdx.x * blockDim.x + tid) >> 6;
    const float bias1 = b1[lane], bias2 = b2[lane];
    for (int n = gw; n < n_nodes; n += nwaves) {
        const int nu = __builtin_amdgcn_readfirstlane(n);
        const float* ar = agg + (size_t)nu * NF;  // wave-uniform -> scalar loads
        float t = bias1;
        #pragma unroll
        for (int k = 0; k < NF; ++k) t = fmaf(ar[k], w1T[k][lane], t);
        const float s = sspf(t);
        float o = bias2;
        #pragma unroll
        for (int k = 0; k < NF; ++k) o = fmaf(__shfl(s, k), w2T[k][lane], o);
        out[(size_t)nu * NF + lane] = o;
    }
}

extern "C" void kernel_launch(void* const* d_in, const int* in_sizes, int n_in,
                              void* d_out, int out_size, void* d_ws, size_t ws_size,
                              hipStream_t stream) {
    const int*   nbr   = (const int*)d_in[0];
    const float* dist  = (const float*)d_in[1];
    const float* x     = (const float*)d_in[2];
    const float* lin_w = (const float*)d_in[3];
    const float* lin_b = (const float*)d_in[4];
    const float* f_w1  = (const float*)d_in[5];
    const float* f_b1  = (const float*)d_in[6];
    const float* f_w2  = (const float*)d_in[7];
    const float* f_b2  = (const float*)d_in[8];
    const float* m_w1  = (const float*)d_in[9];
    const float* m_b1  = (const float*)d_in[10];
    const float* m_w2  = (const float*)d_in[11];
    const float* m_b2  = (const float*)d_in[12];

    const int n_edges = in_sizes[1];
    const int n_nodes = in_sizes[2] / NF;

    float* out   = (float*)d_out;
    float* h     = out;                 // reuse d_out as h scratch (dead before final write)
    float* agg   = (float*)d_ws;        // n_nodes*NF floats
    float* table = agg + (size_t)n_nodes * NF;  // TBL*NF floats

    hipMemsetAsync(agg, 0, (size_t)n_nodes * NF * sizeof(float), stream);
    build_table_k<<<TBL, 64, 0, stream>>>(f_w1, f_b1, f_w2, f_b2, table);
    node_lin_k<<<1024, 256, 0, stream>>>(x, lin_w, lin_b, h, n_nodes);
    edge_k<<<2048, 256, 0, stream>>>(nbr, dist, h, table, agg, n_edges);
    out_mlp_k<<<1024, 256, 0, stream>>>(agg, m_w1, m_b1, m_w2, m_b2, out, n_nodes);
}

// Round 2
// 430.869 us; speedup vs baseline: 1.2997x; 1.2997x over previous
//
#include <hip/hip_runtime.h>

#define NF 64
#define KEXP 50
#define TBL 8192
#define CUTF 5.0f
#define LOG2C 0.6931471805599453f
#define SCAN_BS 1024

__device__ __forceinline__ float sspf(float x) {
    return fmaxf(x, 0.0f) + log1pf(expf(-fabsf(x))) - LOG2C;
}

__device__ __forceinline__ float bcast(float v, int k) {
    return __int_as_float(__builtin_amdgcn_readlane(__float_as_int(v), k));
}

// ---------------------------------------------------------------------------
// filt(d) lookup table: TBL x NF
// ---------------------------------------------------------------------------
__global__ void build_table_k(const float* __restrict__ f_w1, const float* __restrict__ f_b1,
                              const float* __restrict__ f_w2, const float* __restrict__ f_b2,
                              float* __restrict__ table) {
    __shared__ float rbf_s[KEXP];
    __shared__ float s_s[NF];
    const int t = blockIdx.x;
    const int f = threadIdx.x; // 0..63
    const float d = (float)t * (CUTF / (float)(TBL - 1));
    const float delta = CUTF / (float)(KEXP - 1);
    const float coeff = -0.5f / (delta * delta);
    if (f < KEXP) {
        float dd = d - (float)f * delta;
        rbf_s[f] = expf(coeff * dd * dd);
    }
    __syncthreads();
    float t1 = f_b1[f];
    for (int k = 0; k < KEXP; ++k) t1 = fmaf(rbf_s[k], f_w1[f * KEXP + k], t1);
    s_s[f] = sspf(t1);
    __syncthreads();
    float t2 = f_b2[f];
    for (int k = 0; k < NF; ++k) t2 = fmaf(s_s[k], f_w2[f * NF + k], t2);
    table[t * NF + f] = t2;
}

// ---------------------------------------------------------------------------
// prep: h = x @ lin_w.T + lin_b  (wave/node, weights in VGPR, readlane bcast)
//       + (optionally) count edges per dst node
// ---------------------------------------------------------------------------
__global__ void __launch_bounds__(256) prep_k(
    const float* __restrict__ x, const float* __restrict__ w, const float* __restrict__ b,
    float* __restrict__ h, int n_nodes,
    const int* __restrict__ dstrow, unsigned* __restrict__ counts, int n_edges)
{
    const int tid = threadIdx.x;
    const int lane = tid & 63;
    float wreg[NF];
    #pragma unroll
    for (int k = 0; k < NF; k += 4) {
        float4 q = *(const float4*)(w + (size_t)lane * NF + k);
        wreg[k] = q.x; wreg[k + 1] = q.y; wreg[k + 2] = q.z; wreg[k + 3] = q.w;
    }
    const float bias = b[lane];
    const int nwaves = (gridDim.x * blockDim.x) >> 6;
    const int gw = (blockIdx.x * blockDim.x + tid) >> 6;
    for (int n = gw; n < n_nodes; n += nwaves) {
        const float xv = x[(size_t)n * NF + lane];
        float a0 = bias, a1 = 0.f, a2 = 0.f, a3 = 0.f;
        #pragma unroll
        for (int k = 0; k < NF; k += 4) {
            a0 = fmaf(bcast(xv, k),     wreg[k],     a0);
            a1 = fmaf(bcast(xv, k + 1), wreg[k + 1], a1);
            a2 = fmaf(bcast(xv, k + 2), wreg[k + 2], a2);
            a3 = fmaf(bcast(xv, k + 3), wreg[k + 3], a3);
        }
        h[(size_t)n * NF + lane] = (a0 + a1) + (a2 + a3);
    }
    if (counts) {
        const int gt = blockIdx.x * blockDim.x + tid;
        const int gs = gridDim.x * blockDim.x;
        for (int e = gt; e < n_edges; e += gs)
            atomicAdd(&counts[dstrow[e]], 1u);
    }
}

// ---------------------------------------------------------------------------
// 3-kernel exclusive scan over counts[0..n-1] -> offs[0..n]
// ---------------------------------------------------------------------------
__global__ void __launch_bounds__(SCAN_BS) scan1_k(const unsigned* __restrict__ counts,
                                                   unsigned* __restrict__ offs,
                                                   unsigned* __restrict__ bsum, int n) {
    __shared__ unsigned s[SCAN_BS];
    const int t = threadIdx.x;
    const int i = blockIdx.x * SCAN_BS + t;
    const unsigned c = (i < n) ? counts[i] : 0u;
    s[t] = c;
    __syncthreads();
    unsigned run = c;
    for (int d = 1; d < SCAN_BS; d <<= 1) {
        unsigned add = (t >= d) ? s[t - d] : 0u;
        __syncthreads();
        run += add;
        s[t] = run;
        __syncthreads();
    }
    if (i < n) offs[i] = run - c;              // block-local exclusive
    if (t == SCAN_BS - 1) bsum[blockIdx.x] = run;
}

__global__ void __launch_bounds__(SCAN_BS) scan2_k(const unsigned* __restrict__ bsum,
                                                   unsigned* __restrict__ bbase, int nb) {
    __shared__ unsigned s[SCAN_BS];
    const int t = threadIdx.x;
    const unsigned c = (t < nb) ? bsum[t] : 0u;
    s[t] = c;
    __syncthreads();
    unsigned run = c;
    for (int d = 1; d < SCAN_BS; d <<= 1) {
        unsigned add = (t >= d) ? s[t - d] : 0u;
        __syncthreads();
        run += add;
        s[t] = run;
        __syncthreads();
    }
    if (t < nb) bbase[t] = run - c;
}

__global__ void __launch_bounds__(SCAN_BS) scan3_k(unsigned* __restrict__ offs,
                                                   const unsigned* __restrict__ bbase,
                                                   unsigned* __restrict__ cursor,
                                                   int n, int n_edges) {
    const int t = threadIdx.x;
    const int i = blockIdx.x * SCAN_BS + t;
    if (i < n) {
        const unsigned v = offs[i] + bbase[blockIdx.x];
        offs[i] = v;
        cursor[i] = v;
    }
    if (i == 0) offs[n] = (unsigned)n_edges;
}

// ---------------------------------------------------------------------------
// scatter edges into dst-bucketed payload: (src, i0<<16 | frac16)
// ---------------------------------------------------------------------------
__global__ void __launch_bounds__(256) scatter_k(const int* __restrict__ nbr,
                                                 const float* __restrict__ dist,
                                                 unsigned* __restrict__ cursor,
                                                 uint2* __restrict__ payload, int n_edges) {
    const float scale = (float)(TBL - 1) / CUTF;
    const int gt = blockIdx.x * blockDim.x + threadIdx.x;
    const int gs = gridDim.x * blockDim.x;
    for (int e = gt; e < n_edges; e += gs) {
        const int dstn = nbr[n_edges + e];
        const unsigned srcn = (unsigned)nbr[e];
        const float xx = dist[e] * scale;
        int i0 = (int)xx;
        i0 = max(0, min(i0, TBL - 2));
        float fr = xx - (float)i0;
        unsigned f16 = (unsigned)(fr * 65536.0f);
        f16 = min(f16, 65535u);
        const unsigned pos = atomicAdd(&cursor[dstn], 1u);
        payload[pos] = make_uint2(srcn, ((unsigned)i0 << 16) | f16);
    }
}

// ---------------------------------------------------------------------------
// aggregate: wave per node, register accumulation, single coalesced write
// ---------------------------------------------------------------------------
__global__ void __launch_bounds__(256) agg_k(const unsigned* __restrict__ offs,
                                             const uint2* __restrict__ payload,
                                             const float* __restrict__ h,
                                             const float* __restrict__ table,
                                             float* __restrict__ agg, int n_nodes) {
    const int tid = threadIdx.x;
    const int lane = tid & 63;
    const int nwaves = (gridDim.x * blockDim.x) >> 6;
    const int gw = (blockIdx.x * blockDim.x + tid) >> 6;
    for (int n = gw; n < n_nodes; n += nwaves) {
        const unsigned beg = offs[n], end = offs[n + 1];
        float acc0 = 0.f, acc1 = 0.f;
        for (unsigned base = beg; base < end; base += 64u) {
            const int m = (int)min(64u, end - base);
            uint2 pl = make_uint2(0u, 0u);
            if (lane < m) pl = payload[base + lane];
            #pragma unroll 4
            for (int j = 0; j < m; ++j) {
                const unsigned sj = (unsigned)__shfl((int)pl.x, j);
                const unsigned w2 = (unsigned)__shfl((int)pl.y, j);
                const int ij = (int)(w2 >> 16);
                const float fj = (float)(w2 & 0xffffu) * (1.0f / 65536.0f);
                const float* tp = table + (size_t)ij * NF;
                const float t0 = tp[lane];
                const float t1 = tp[NF + lane];
                const float hv = h[(size_t)sj * NF + lane];
                const float filt = fmaf(fj, t1 - t0, t0);
                if (j & 1) acc1 = fmaf(hv, filt, acc1);
                else       acc0 = fmaf(hv, filt, acc0);
            }
        }
        agg[(size_t)n * NF + lane] = acc0 + acc1;
    }
}

// ---------------------------------------------------------------------------
// fallback edge kernel (atomic scatter-add) — used only if ws too small
// ---------------------------------------------------------------------------
__global__ void edge_k(const int* __restrict__ nbr, const float* __restrict__ dist,
                       const float* __restrict__ h, const float* __restrict__ table,
                       float* __restrict__ agg, int n_edges) {
    const int tid = threadIdx.x;
    const int lane = tid & 63;
    const int nwaves = (gridDim.x * blockDim.x) >> 6;
    const int gw = (blockIdx.x * blockDim.x + tid) >> 6;
    const float scale = (float)(TBL - 1) / CUTF;
    const int nbatch = n_edges >> 6;
    for (int bb = gw; bb < nbatch; bb += nwaves) {
        const int e0 = bb << 6;
        int src = nbr[e0 + lane];
        int dst = nbr[n_edges + e0 + lane];
        float d = dist[e0 + lane];
        float xx = d * scale;
        int i0 = (int)xx;
        i0 = max(0, min(i0, TBL - 2));
        float frac = xx - (float)i0;
        #pragma unroll 4
        for (int j = 0; j < 64; ++j) {
            const int sj = __shfl(src, j);
            const int dj = __shfl(dst, j);
            const int ij = __shfl(i0, j);
            const float fj = __shfl(frac, j);
            const float t0 = table[ij * NF + lane];
            const float t1 = table[ij * NF + NF + lane];
            const float filt = fmaf(fj, t1 - t0, t0);
            const float hv = h[(size_t)sj * NF + lane];
            atomicAdd(agg + (size_t)dj * NF + lane, hv * filt);
        }
    }
    if (gw == 0) {
        for (int e = nbatch << 6; e < n_edges; ++e) {
            const int sj = nbr[e];
            const int dj = nbr[n_edges + e];
            const float d = dist[e];
            float xx = d * scale;
            int ij = (int)xx;
            ij = max(0, min(ij, TBL - 2));
            const float fj = xx - (float)ij;
            const float t0 = table[ij * NF + lane];
            const float t1 = table[ij * NF + NF + lane];
            const float filt = fmaf(fj, t1 - t0, t0);
            const float hv = h[(size_t)sj * NF + lane];
            atomicAdd(agg + (size_t)dj * NF + lane, hv * filt);
        }
    }
}

// ---------------------------------------------------------------------------
// out = ssp(agg @ m_w1.T + m_b1) @ m_w2.T + m_b2  (wave/node, weights in VGPR)
// ---------------------------------------------------------------------------
__global__ void __launch_bounds__(256) out_mlp_k(const float* __restrict__ agg,
                                                 const float* __restrict__ w1,
                                                 const float* __restrict__ b1,
                                                 const float* __restrict__ w2,
                                                 const float* __restrict__ b2,
                                                 float* __restrict__ out, int n_nodes) {
    const int tid = threadIdx.x;
    const int lane = tid & 63;
    float w1reg[NF], w2reg[NF];
    #pragma unroll
    for (int k = 0; k < NF; k += 4) {
        float4 q1 = *(const float4*)(w1 + (size_t)lane * NF + k);
        w1reg[k] = q1.x; w1reg[k + 1] = q1.y; w1reg[k + 2] = q1.z; w1reg[k + 3] = q1.w;
        float4 q2 = *(const float4*)(w2 + (size_t)lane * NF + k);
        w2reg[k] = q2.x; w2reg[k + 1] = q2.y; w2reg[k + 2] = q2.z; w2reg[k + 3] = q2.w;
    }
    const float bias1 = b1[lane], bias2 = b2[lane];
    const int nwaves = (gridDim.x * blockDim.x) >> 6;
    const int gw = (blockIdx.x * blockDim.x + tid) >> 6;
    for (int n = gw; n < n_nodes; n += nwaves) {
        const float av = agg[(size_t)n * NF + lane];
        float a0 = bias1, a1 = 0.f, a2 = 0.f, a3 = 0.f;
        #pragma unroll
        for (int k = 0; k < NF; k += 4) {
            a0 = fmaf(bcast(av, k),     w1reg[k],     a0);
            a1 = fmaf(bcast(av, k + 1), w1reg[k + 1], a1);
            a2 = fmaf(bcast(av, k + 2), w1reg[k + 2], a2);
            a3 = fmaf(bcast(av, k + 3), w1reg[k + 3], a3);
        }
        const float s = sspf((a0 + a1) + (a2 + a3));
        float o0 = bias2, o1 = 0.f, o2 = 0.f, o3 = 0.f;
        #pragma unroll
        for (int k = 0; k < NF; k += 4) {
            o0 = fmaf(bcast(s, k),     w2reg[k],     o0);
            o1 = fmaf(bcast(s, k + 1), w2reg[k + 1], o1);
            o2 = fmaf(bcast(s, k + 2), w2reg[k + 2], o2);
            o3 = fmaf(bcast(s, k + 3), w2reg[k + 3], o3);
        }
        out[(size_t)n * NF + lane] = (o0 + o1) + (o2 + o3);
    }
}

extern "C" void kernel_launch(void* const* d_in, const int* in_sizes, int n_in,
                              void* d_out, int out_size, void* d_ws, size_t ws_size,
                              hipStream_t stream) {
    const int*   nbr   = (const int*)d_in[0];
    const float* dist  = (const float*)d_in[1];
    const float* x     = (const float*)d_in[2];
    const float* lin_w = (const float*)d_in[3];
    const float* lin_b = (const float*)d_in[4];
    const float* f_w1  = (const float*)d_in[5];
    const float* f_b1  = (const float*)d_in[6];
    const float* f_w2  = (const float*)d_in[7];
    const float* f_b2  = (const float*)d_in[8];
    const float* m_w1  = (const float*)d_in[9];
    const float* m_b1  = (const float*)d_in[10];
    const float* m_w2  = (const float*)d_in[11];
    const float* m_b2  = (const float*)d_in[12];

    const int n_edges = in_sizes[1];
    const int n_nodes = in_sizes[2] / NF;

    float* out = (float*)d_out;
    float* h   = out;  // d_out reused as h scratch (dead before final MLP write)

    // workspace layout
    char* ws = (char*)d_ws;
    size_t off = 0;
    auto alloc = [&](size_t bytes) { char* p = ws + off; off = (off + bytes + 255) & ~(size_t)255; return p; };
    float*    agg     = (float*)alloc((size_t)n_nodes * NF * sizeof(float));
    float*    table   = (float*)alloc((size_t)TBL * NF * sizeof(float));
    unsigned* counts  = (unsigned*)alloc((size_t)n_nodes * sizeof(unsigned));      // becomes cursor
    unsigned* offs    = (unsigned*)alloc((size_t)(n_nodes + 1) * sizeof(unsigned));
    unsigned* bsum    = (unsigned*)alloc(SCAN_BS * sizeof(unsigned));
    unsigned* bbase   = (unsigned*)alloc(SCAN_BS * sizeof(unsigned));
    uint2*    payload = (uint2*)alloc((size_t)n_edges * sizeof(uint2));
    const bool sorted_path = (off <= ws_size);

    build_table_k<<<TBL, 64, 0, stream>>>(f_w1, f_b1, f_w2, f_b2, table);

    if (sorted_path) {
        hipMemsetAsync(counts, 0, (size_t)n_nodes * sizeof(unsigned), stream);
        prep_k<<<2048, 256, 0, stream>>>(x, lin_w, lin_b, h, n_nodes,
                                         nbr + n_edges, counts, n_edges);
        const int nb = (n_nodes + SCAN_BS - 1) / SCAN_BS;
        scan1_k<<<nb, SCAN_BS, 0, stream>>>(counts, offs, bsum, n_nodes);
        scan2_k<<<1, SCAN_BS, 0, stream>>>(bsum, bbase, nb);
        scan3_k<<<nb, SCAN_BS, 0, stream>>>(offs, bbase, counts, n_nodes, n_edges);
        scatter_k<<<2048, 256, 0, stream>>>(nbr, dist, counts, payload, n_edges);
        agg_k<<<2048, 256, 0, stream>>>(offs, payload, h, table, agg, n_nodes);
    } else {
        hipMemsetAsync(agg, 0, (size_t)n_nodes * NF * sizeof(float), stream);
        prep_k<<<2048, 256, 0, stream>>>(x, lin_w, lin_b, h, n_nodes,
                                         (const int*)nullptr, (unsigned*)nullptr, 0);
        edge_k<<<2048, 256, 0, stream>>>(nbr, dist, h, table, agg, n_edges);
    }
    out_mlp_k<<<1024, 256, 0, stream>>>(agg, m_w1, m_b1, m_w2, m_b2, out, n_nodes);
}